// Round 3
// baseline (70.295 us; speedup 1.0000x reference)
//
#include <hip/hip_runtime.h>
#include <math.h>

// FinalGNN: b=16, n=256, feature=64
// ws layout (floats):
#define OFF_H      0
#define OFF_HT     262144
#define OFF_AI     (262144*2)
#define OFF_AJT    (262144*3)
#define OFF_SQ     (262144*4)
#define OFF_HRES   (262144*4 + 4096)

__device__ __forceinline__ float elu_f(float x) { return x > 0.f ? x : expm1f(x); }

// K1: h = elu(x@proj_w + proj_b); a_i = h@s_w1[:64] + s_b1; a_j = h@s_w1[64:]; sq = sum(h*h)
// 512 blocks x 256 threads; block = 8 rows, wave = 2 rows. s_w1 staged in LDS (32KB).
__global__ __launch_bounds__(256) void k1_embed(
    const float* __restrict__ x,
    const float* __restrict__ proj_w, const float* __restrict__ proj_b,
    const float* __restrict__ s_w1, const float* __restrict__ s_b1,
    float* __restrict__ h, float* __restrict__ hT,
    float* __restrict__ a_i, float* __restrict__ a_jT,
    float* __restrict__ sq)
{
    __shared__ float w_sh[8192];   // s_w1 [128][64]
    int tid = threadIdx.x;
    #pragma unroll
    for (int r = 0; r < 8; ++r) {
        float4 v = *(const float4*)&s_w1[(r*256 + tid)*4];
        *(float4*)&w_sh[(r*256 + tid)*4] = v;
    }
    __syncthreads();

    int lane = tid & 63;
    int wave = tid >> 6;
    int row0 = blockIdx.x * 8;

    float pw0 = proj_w[lane], pw1 = proj_w[64+lane], pw2 = proj_w[128+lane],
          pw3 = proj_w[192+lane], pb = proj_b[lane], b1 = s_b1[lane];

    #pragma unroll
    for (int r = 0; r < 2; ++r) {
        int row = row0 + wave*2 + r;          // b*256 + i
        int b = row >> 8, i = row & 255;
        float hv = x[row*4+0]*pw0 + x[row*4+1]*pw1 + x[row*4+2]*pw2
                 + x[row*4+3]*pw3 + pb;
        hv = elu_f(hv);

        float ai = b1, aj = 0.f, sqv = 0.f;
        #pragma unroll 8
        for (int e = 0; e < 64; ++e) {
            float he = __shfl(hv, e);
            ai  = fmaf(he, w_sh[e*64 + lane], ai);
            aj  = fmaf(he, w_sh[(64+e)*64 + lane], aj);
            sqv = fmaf(he, he, sqv);
        }
        h[row*64 + lane] = hv;
        hT[b*64*256 + lane*256 + i] = hv;
        a_i[row*64 + lane] = ai;
        a_jT[b*64*256 + lane*256 + i] = aj;
        if (lane == 0) sq[row] = sqv;
    }
}

// K2: block = (b, 8 consecutive i rows); thread = j in [0,256).
// pass1: LN stats + gram dot; pass2: recompute pre, LN->relu->dot(w2);
// sigma/adj; aggregation adj@h; fused gnn GEMV + residual + elu -> h_res.
#define TI 8
__global__ __launch_bounds__(256) void k2_pair(
    const float* __restrict__ a_i, const float* __restrict__ a_jT,
    const float* __restrict__ hT, const float* __restrict__ h,
    const float* __restrict__ sq,
    const float* __restrict__ ln_g, const float* __restrict__ ln_b,
    const float* __restrict__ s_w2, const float* __restrict__ s_b2,
    const float* __restrict__ gnn_w,
    float* __restrict__ h_res)
{
    int bi0 = blockIdx.x * TI;         // first row (b*256 + i0)
    int b   = bi0 >> 8;
    int j   = threadIdx.x;

    __shared__ float ai_sh[TI][64], hi_sh[TI][64];
    __shared__ float g_sh[64], be_sh[64], w2_sh[64];
    __shared__ float adj_sh[256][TI];          // [j][i]
    __shared__ float part_sh[4][TI][64];
    __shared__ float hagg_sh[TI][64];
    __shared__ float gnn_sh[4096];

    if (j < 64) { g_sh[j] = ln_g[j]; be_sh[j] = ln_b[j]; w2_sh[j] = s_w2[j]; }
    #pragma unroll
    for (int r = 0; r < 2; ++r) {
        int idx = r*256 + j;
        int i = idx >> 6, d = idx & 63;
        ai_sh[i][d] = a_i[(bi0 + i)*64 + d];
        hi_sh[i][d] = h[(bi0 + i)*64 + d];
    }
    #pragma unroll
    for (int r = 0; r < 4; ++r) {
        *(float4*)&gnn_sh[(r*256 + j)*4] = *(const float4*)&gnn_w[(r*256 + j)*4];
    }
    __syncthreads();

    const float* ajb = a_jT + b*64*256;
    const float* htb = hT   + b*64*256;

    // ---- pass 1: stats + gram dot ----
    float ps[TI], pss[TI], dt[TI];
    #pragma unroll
    for (int i = 0; i < TI; ++i) { ps[i] = 0.f; pss[i] = 0.f; dt[i] = 0.f; }
    #pragma unroll 8
    for (int d = 0; d < 64; ++d) {
        float ajd = ajb[d*256 + j];
        float hjd = htb[d*256 + j];
        #pragma unroll
        for (int i = 0; i < TI; ++i) {
            float pre = ai_sh[i][d] + ajd;
            ps[i]  += pre;
            pss[i]  = fmaf(pre, pre, pss[i]);
            dt[i]   = fmaf(hi_sh[i][d], hjd, dt[i]);
        }
    }
    float rs[TI], nmurs[TI];
    #pragma unroll
    for (int i = 0; i < TI; ++i) {
        float mu  = ps[i] * (1.f/64.f);
        float var = pss[i] * (1.f/64.f) - mu*mu;
        rs[i]    = rsqrtf(var + 1e-5f);
        nmurs[i] = -mu * rs[i];
    }

    // ---- pass 2: LN -> relu -> dot(w2) ----
    float acc[TI];
    #pragma unroll
    for (int i = 0; i < TI; ++i) acc[i] = 0.f;
    #pragma unroll 8
    for (int d = 0; d < 64; ++d) {
        float ajd = ajb[d*256 + j];
        float gd = g_sh[d], bd = be_sh[d], wd = w2_sh[d];
        #pragma unroll
        for (int i = 0; i < TI; ++i) {
            float pre = ai_sh[i][d] + ajd;
            float v   = fmaf(pre, rs[i], nmurs[i]);
            float t   = fmaf(v, gd, bd);
            t = fmaxf(t, 0.f);
            acc[i] = fmaf(t, wd, acc[i]);
        }
    }

    // ---- sigma, adj ----
    float b2  = s_b2[0];
    float sqj = sq[b*256 + j];
    #pragma unroll
    for (int i = 0; i < TI; ++i) {
        float sp  = acc[i] + b2;
        float sig = fmaxf(sp, 0.f) + log1pf(expf(-fabsf(sp)));   // softplus
        float sqi = sq[bi0 + i];
        float d2  = fmaxf(sqi + sqj - 2.f*dt[i], 0.f);
        adj_sh[j][i] = expf(-d2 / (2.f*sig*sig + 1e-6f));
    }
    __syncthreads();

    // ---- aggregation: hagg[i][d] = sum_j adj[i][j] * h[b,j,d] ----
    int d = j & 63, q = j >> 6;
    const float* hb = h + b*256*64;
    float part[TI];
    #pragma unroll
    for (int i = 0; i < TI; ++i) part[i] = 0.f;
    #pragma unroll 4
    for (int k = 0; k < 64; ++k) {
        int jj = q*64 + k;
        float hv = hb[jj*64 + d];                     // coalesced (lanes=d)
        float4 a0 = *(const float4*)&adj_sh[jj][0];   // LDS broadcast
        float4 a1 = *(const float4*)&adj_sh[jj][4];
        part[0] = fmaf(a0.x, hv, part[0]);
        part[1] = fmaf(a0.y, hv, part[1]);
        part[2] = fmaf(a0.z, hv, part[2]);
        part[3] = fmaf(a0.w, hv, part[3]);
        part[4] = fmaf(a1.x, hv, part[4]);
        part[5] = fmaf(a1.y, hv, part[5]);
        part[6] = fmaf(a1.z, hv, part[6]);
        part[7] = fmaf(a1.w, hv, part[7]);
    }
    #pragma unroll
    for (int i = 0; i < TI; ++i) part_sh[q][i][d] = part[i];
    __syncthreads();
    #pragma unroll
    for (int r = 0; r < 2; ++r) {
        int idx = r*256 + j;
        int i = idx >> 6, dd = idx & 63;
        hagg_sh[i][dd] = part_sh[0][i][dd] + part_sh[1][i][dd]
                       + part_sh[2][i][dd] + part_sh[3][i][dd];
    }
    __syncthreads();

    // ---- fused gnn: h_res = elu(hagg @ gnn_w + h) ----
    {
        int lane = j & 63, wave = j >> 6;
        int r0 = wave, r1 = wave + 4;
        float acc0 = 0.f, acc1 = 0.f;
        #pragma unroll 8
        for (int e = 0; e < 64; ++e) {
            float g = gnn_sh[e*64 + lane];
            acc0 = fmaf(hagg_sh[r0][e], g, acc0);
            acc1 = fmaf(hagg_sh[r1][e], g, acc1);
        }
        h_res[(bi0 + r0)*64 + lane] = elu_f(acc0 + hi_sh[r0][lane]);
        h_res[(bi0 + r1)*64 + lane] = elu_f(acc1 + hi_sh[r1][lane]);
    }
}

// K4: pooled = [mean_i, max_i]; classifier.  16 blocks x 256 threads.
__global__ __launch_bounds__(256) void k4_pool_cls(
    const float* __restrict__ h_res,
    const float* __restrict__ c_w1, const float* __restrict__ c_b1,
    const float* __restrict__ bn_g, const float* __restrict__ bn_b,
    const float* __restrict__ bn_mean, const float* __restrict__ bn_var,
    const float* __restrict__ c_w2, const float* __restrict__ c_b2,
    float* __restrict__ out)
{
    int b = blockIdx.x;
    int tid = threadIdx.x;
    int d = tid & 63, q = tid >> 6;
    const float* hb = h_res + b*256*64;

    float sum = 0.f, mx = -INFINITY;
    #pragma unroll 8
    for (int k = 0; k < 64; ++k) {
        float v = hb[(q*64+k)*64 + d];
        sum += v; mx = fmaxf(mx, v);
    }
    __shared__ float sum_sh[256], max_sh[256];
    __shared__ float pm_sh[64], px_sh[64];
    sum_sh[tid] = sum; max_sh[tid] = mx;
    __syncthreads();
    if (tid < 64) {
        float tsum = sum_sh[tid] + sum_sh[64+tid] + sum_sh[128+tid] + sum_sh[192+tid];
        float tmax = fmaxf(fmaxf(max_sh[tid], max_sh[64+tid]),
                           fmaxf(max_sh[128+tid], max_sh[192+tid]));
        pm_sh[tid] = tsum * (1.f/256.f);
        px_sh[tid] = tmax;
    }
    __syncthreads();
    if (tid < 64) {
        float acc = c_b1[tid];
        #pragma unroll
        for (int e = 0; e < 64; ++e) {
            acc += pm_sh[e] * c_w1[e*64 + tid];
            acc += px_sh[e] * c_w1[(64+e)*64 + tid];
        }
        float z = (acc - bn_mean[tid]) * rsqrtf(bn_var[tid] + 1e-5f) * bn_g[tid] + bn_b[tid];
        z = elu_f(z);
        float c0 = z * c_w2[tid*2 + 0];
        float c1 = z * c_w2[tid*2 + 1];
        for (int off = 32; off > 0; off >>= 1) {
            c0 += __shfl_down(c0, off);
            c1 += __shfl_down(c1, off);
        }
        if (tid == 0) {
            out[b*2 + 0] = c0 + c_b2[0];
            out[b*2 + 1] = c1 + c_b2[1];
        }
    }
}

extern "C" void kernel_launch(void* const* d_in, const int* in_sizes, int n_in,
                              void* d_out, int out_size, void* d_ws, size_t ws_size,
                              hipStream_t stream) {
    const float* x       = (const float*)d_in[0];
    const float* proj_w  = (const float*)d_in[1];
    const float* proj_b  = (const float*)d_in[2];
    const float* s_w1    = (const float*)d_in[3];
    const float* s_b1    = (const float*)d_in[4];
    const float* ln_g    = (const float*)d_in[5];
    const float* ln_b    = (const float*)d_in[6];
    const float* s_w2    = (const float*)d_in[7];
    const float* s_b2    = (const float*)d_in[8];
    const float* gnn_w   = (const float*)d_in[9];
    const float* c_w1    = (const float*)d_in[10];
    const float* c_b1    = (const float*)d_in[11];
    const float* bn_g    = (const float*)d_in[12];
    const float* bn_b    = (const float*)d_in[13];
    const float* bn_mean = (const float*)d_in[14];
    const float* bn_var  = (const float*)d_in[15];
    const float* c_w2    = (const float*)d_in[16];
    const float* c_b2    = (const float*)d_in[17];

    float* w = (float*)d_ws;
    float* h     = w + OFF_H;
    float* hT    = w + OFF_HT;
    float* a_i   = w + OFF_AI;
    float* a_jT  = w + OFF_AJT;
    float* sq    = w + OFF_SQ;
    float* h_res = w + OFF_HRES;
    float* out   = (float*)d_out;

    k1_embed<<<512, 256, 0, stream>>>(x, proj_w, proj_b, s_w1, s_b1,
                                      h, hT, a_i, a_jT, sq);
    k2_pair<<<512, 256, 0, stream>>>(a_i, a_jT, hT, h, sq,
                                     ln_g, ln_b, s_w2, s_b2, gnn_w, h_res);
    k4_pool_cls<<<16, 256, 0, stream>>>(h_res, c_w1, c_b1, bn_g, bn_b,
                                        bn_mean, bn_var, c_w2, c_b2, out);
}

// Round 5
// 60.547 us; speedup vs baseline: 1.1610x; 1.1610x over previous
//
#include <hip/hip_runtime.h>
#include <math.h>

// FinalGNN: b=16, n=256, feature=64
// ws layout (floats):
#define OFF_H      0                    // h    [16][256][64]
#define OFF_HT     262144               // hT   [16][64][256]
#define OFF_AI     524288               // a_i  [16][256][64]  (includes s_b1)
#define OFF_AJT    786432               // a_jT [16][64][256]
#define OFF_SAI    1048576              // per-row scalars, 4096 each
#define OFF_QAI    1052672
#define OFF_SAJ    1056768
#define OFF_QAJ    1060864
#define OFF_SQH    1064960
#define OFF_RS     1069056              // rs   [4096][256]
#define OFF_NR     2117632              // -mu*rs
#define OFF_D2     3166208              // d2
#define OFF_HRES   4214784              // h_res [16][256][64]
// total 4,476,928 floats = 17.9 MB

__device__ __forceinline__ float elu_f(float x) { return x > 0.f ? x : expm1f(x); }

// K1: h = elu(x@proj_w+proj_b); a_i = h@s_w1[:64]+s_b1; a_j = h@s_w1[64:];
//     row scalars: sa_i, qa_i, sa_j, qa_j, sqh.  512 blocks x 256 thr.
__global__ __launch_bounds__(256) void k1_embed(
    const float* __restrict__ x,
    const float* __restrict__ proj_w, const float* __restrict__ proj_b,
    const float* __restrict__ s_w1, const float* __restrict__ s_b1,
    float* __restrict__ h, float* __restrict__ hT,
    float* __restrict__ a_i, float* __restrict__ a_jT,
    float* __restrict__ sa_i, float* __restrict__ qa_i,
    float* __restrict__ sa_j, float* __restrict__ qa_j,
    float* __restrict__ sqh)
{
    __shared__ float w_sh[8192];   // s_w1 [128][64]
    int tid = threadIdx.x;
    #pragma unroll
    for (int r = 0; r < 8; ++r)
        *(float4*)&w_sh[(r*256 + tid)*4] = *(const float4*)&s_w1[(r*256 + tid)*4];
    __syncthreads();

    int lane = tid & 63;
    int wave = tid >> 6;
    int row0 = blockIdx.x * 8;

    float pw0 = proj_w[lane], pw1 = proj_w[64+lane], pw2 = proj_w[128+lane],
          pw3 = proj_w[192+lane], pb = proj_b[lane], b1 = s_b1[lane];

    #pragma unroll
    for (int r = 0; r < 2; ++r) {
        int row = row0 + wave*2 + r;          // b*256 + i
        int b = row >> 8, i = row & 255;
        float4 xv = *(const float4*)&x[row*4];
        float hv = elu_f(xv.x*pw0 + xv.y*pw1 + xv.z*pw2 + xv.w*pw3 + pb);

        float ai = b1, aj = 0.f, sqv = 0.f;
        #pragma unroll 8
        for (int e = 0; e < 64; ++e) {
            float he = __shfl(hv, e);
            ai  = fmaf(he, w_sh[e*64 + lane], ai);
            aj  = fmaf(he, w_sh[(64+e)*64 + lane], aj);
            sqv = fmaf(he, he, sqv);
        }
        h[row*64 + lane] = hv;
        hT[b*64*256 + lane*256 + i] = hv;
        a_i[row*64 + lane] = ai;
        a_jT[b*64*256 + lane*256 + i] = aj;

        float v1 = ai, v2 = ai*ai, v3 = aj, v4 = aj*aj;
        #pragma unroll
        for (int off = 32; off > 0; off >>= 1) {
            v1 += __shfl_xor(v1, off);
            v2 += __shfl_xor(v2, off);
            v3 += __shfl_xor(v3, off);
            v4 += __shfl_xor(v4, off);
        }
        if (lane == 0) {
            sa_i[row] = v1; qa_i[row] = v2;
            sa_j[row] = v3; qa_j[row] = v4;
            sqh[row]  = sqv;
        }
    }
}

// K2: cross-grams ga = a_i . a_j, gh = h_i . h_j, then per-pair LN stats + d2.
// 512 blocks x 256 thr; block = (b, 8-i strip), thread = one j, 8 i's.
__global__ __launch_bounds__(256) void k2_gram(
    const float* __restrict__ a_i, const float* __restrict__ a_jT,
    const float* __restrict__ h, const float* __restrict__ hT,
    const float* __restrict__ sa_i, const float* __restrict__ qa_i,
    const float* __restrict__ sa_j, const float* __restrict__ qa_j,
    const float* __restrict__ sqh,
    float* __restrict__ rs_m, float* __restrict__ nr_m, float* __restrict__ d2_m)
{
    int bi0 = blockIdx.x * 8;
    int b   = bi0 >> 8;
    int j   = threadIdx.x;

    __shared__ float aiT[64][8], hiT[64][8];     // [d][i]
    __shared__ float sai_s[8], qai_s[8], sqi_s[8];

    #pragma unroll
    for (int rep = 0; rep < 2; ++rep) {
        int idx = rep*256 + j;
        int ii = idx >> 6, d = idx & 63;         // ii in 0..7 across reps (FIXED)
        aiT[d][ii] = a_i[(bi0+ii)*64 + d];
        hiT[d][ii] = h[(bi0+ii)*64 + d];
    }
    if (j < 8) {
        sai_s[j] = sa_i[bi0+j]; qai_s[j] = qa_i[bi0+j]; sqi_s[j] = sqh[bi0+j];
    }
    __syncthreads();

    const float* ajb = a_jT + b*64*256;
    const float* htb = hT   + b*64*256;

    float ga[8], gh[8];
    #pragma unroll
    for (int i = 0; i < 8; ++i) { ga[i] = 0.f; gh[i] = 0.f; }

    #pragma unroll 8
    for (int d = 0; d < 64; ++d) {
        float ajd = ajb[d*256 + j];
        float hjd = htb[d*256 + j];
        float4 A0 = *(const float4*)&aiT[d][0];
        float4 A1 = *(const float4*)&aiT[d][4];
        float4 H0 = *(const float4*)&hiT[d][0];
        float4 H1 = *(const float4*)&hiT[d][4];
        ga[0] = fmaf(A0.x, ajd, ga[0]); ga[1] = fmaf(A0.y, ajd, ga[1]);
        ga[2] = fmaf(A0.z, ajd, ga[2]); ga[3] = fmaf(A0.w, ajd, ga[3]);
        ga[4] = fmaf(A1.x, ajd, ga[4]); ga[5] = fmaf(A1.y, ajd, ga[5]);
        ga[6] = fmaf(A1.z, ajd, ga[6]); ga[7] = fmaf(A1.w, ajd, ga[7]);
        gh[0] = fmaf(H0.x, hjd, gh[0]); gh[1] = fmaf(H0.y, hjd, gh[1]);
        gh[2] = fmaf(H0.z, hjd, gh[2]); gh[3] = fmaf(H0.w, hjd, gh[3]);
        gh[4] = fmaf(H1.x, hjd, gh[4]); gh[5] = fmaf(H1.y, hjd, gh[5]);
        gh[6] = fmaf(H1.z, hjd, gh[6]); gh[7] = fmaf(H1.w, hjd, gh[7]);
    }

    float saj = sa_j[b*256 + j], qaj = qa_j[b*256 + j], sqj = sqh[b*256 + j];
    #pragma unroll
    for (int i = 0; i < 8; ++i) {
        float mu  = (sai_s[i] + saj) * (1.f/64.f);
        float pss = qai_s[i] + qaj + 2.f*ga[i];
        float var = pss * (1.f/64.f) - mu*mu;
        float r   = rsqrtf(var + 1e-5f);
        int   o   = (bi0+i)*256 + j;
        rs_m[o] = r;
        nr_m[o] = -mu * r;
        d2_m[o] = fmaxf(sqi_s[i] + sqj - 2.f*gh[i], 0.f);
    }
}

// K3: per block (b, 4-i tile), thread = j. Single d-loop LN->relu->dot(w2),
// sigma/adj, aggregation adj@h, fused gnn GEMV + residual + elu.
__global__ __launch_bounds__(256) void k3_pair(
    const float* __restrict__ a_i, const float* __restrict__ a_jT,
    const float* __restrict__ h,
    const float* __restrict__ rs_m, const float* __restrict__ nr_m,
    const float* __restrict__ d2_m,
    const float* __restrict__ ln_g, const float* __restrict__ ln_b,
    const float* __restrict__ s_w2, const float* __restrict__ s_b2,
    const float* __restrict__ gnn_w,
    float* __restrict__ h_res)
{
    int bi0 = blockIdx.x * 4;
    int b   = bi0 >> 8;
    int j   = threadIdx.x;

    __shared__ float aiT[64][4];        // [d][i] float4
    __shared__ float gbw[64][4];        // {ln_g, ln_b, s_w2, 0}
    __shared__ float hi_sh[4][64];
    __shared__ float adj_sh[256][4];
    __shared__ float part_sh[4][4][64];
    __shared__ float hagg_sh[4][64];

    {
        int i = j >> 6, d = j & 63;
        aiT[d][i]   = a_i[(bi0+i)*64 + d];
        hi_sh[i][d] = h[(bi0+i)*64 + d];
    }
    if (j < 64) {
        gbw[j][0] = ln_g[j]; gbw[j][1] = ln_b[j]; gbw[j][2] = s_w2[j]; gbw[j][3] = 0.f;
    }
    float rs4[4], nr4[4], d24[4];
    #pragma unroll
    for (int i = 0; i < 4; ++i) {
        int o = (bi0+i)*256 + j;
        rs4[i] = rs_m[o]; nr4[i] = nr_m[o]; d24[i] = d2_m[o];
    }
    float b2 = s_b2[0];
    __syncthreads();

    const float* ajb = a_jT + b*64*256;

    float acc[4] = {0.f, 0.f, 0.f, 0.f};
    #pragma unroll 16
    for (int d = 0; d < 64; ++d) {
        float ajd = ajb[d*256 + j];
        float4 A = *(const float4*)&aiT[d][0];
        float4 G = *(const float4*)&gbw[d][0];
        {
            float t = fmaxf(fmaf(fmaf(A.x + ajd, rs4[0], nr4[0]), G.x, G.y), 0.f);
            acc[0] = fmaf(t, G.z, acc[0]);
        }
        {
            float t = fmaxf(fmaf(fmaf(A.y + ajd, rs4[1], nr4[1]), G.x, G.y), 0.f);
            acc[1] = fmaf(t, G.z, acc[1]);
        }
        {
            float t = fmaxf(fmaf(fmaf(A.z + ajd, rs4[2], nr4[2]), G.x, G.y), 0.f);
            acc[2] = fmaf(t, G.z, acc[2]);
        }
        {
            float t = fmaxf(fmaf(fmaf(A.w + ajd, rs4[3], nr4[3]), G.x, G.y), 0.f);
            acc[3] = fmaf(t, G.z, acc[3]);
        }
    }

    #pragma unroll
    for (int i = 0; i < 4; ++i) {
        float sp  = acc[i] + b2;
        float sig = fmaxf(sp, 0.f) + log1pf(expf(-fabsf(sp)));   // softplus
        adj_sh[j][i] = expf(-d24[i] / (2.f*sig*sig + 1e-6f));
    }
    __syncthreads();

    // aggregation: hagg[i][d] = sum_j adj[i][j] * h[b,j,d]
    int d = j & 63, q = j >> 6;
    const float* hb = h + b*256*64;
    float part[4] = {0.f, 0.f, 0.f, 0.f};
    #pragma unroll 8
    for (int k = 0; k < 64; ++k) {
        int jj = q*64 + k;
        float hv = hb[jj*64 + d];                     // coalesced (lanes=d)
        float4 a4 = *(const float4*)&adj_sh[jj][0];   // LDS broadcast
        part[0] = fmaf(a4.x, hv, part[0]);
        part[1] = fmaf(a4.y, hv, part[1]);
        part[2] = fmaf(a4.z, hv, part[2]);
        part[3] = fmaf(a4.w, hv, part[3]);
    }
    #pragma unroll
    for (int i = 0; i < 4; ++i) part_sh[q][i][d] = part[i];
    __syncthreads();

    {
        int i = j >> 6, dd = j & 63;
        hagg_sh[i][dd] = part_sh[0][i][dd] + part_sh[1][i][dd]
                       + part_sh[2][i][dd] + part_sh[3][i][dd];
    }
    __syncthreads();

    // fused gnn: h_res = elu(hagg @ gnn_w + h); gnn_w direct from L1
    {
        int i = j >> 6, lane = j & 63;
        float accg = 0.f;
        #pragma unroll 8
        for (int e = 0; e < 64; ++e)
            accg = fmaf(hagg_sh[i][e], gnn_w[e*64 + lane], accg);
        h_res[(bi0+i)*64 + lane] = elu_f(accg + hi_sh[i][lane]);
    }
}

// K4: pooled = [mean_i, max_i]; classifier.  16 blocks x 256 threads.
__global__ __launch_bounds__(256) void k4_pool_cls(
    const float* __restrict__ h_res,
    const float* __restrict__ c_w1, const float* __restrict__ c_b1,
    const float* __restrict__ bn_g, const float* __restrict__ bn_b,
    const float* __restrict__ bn_mean, const float* __restrict__ bn_var,
    const float* __restrict__ c_w2, const float* __restrict__ c_b2,
    float* __restrict__ out)
{
    int b = blockIdx.x;
    int tid = threadIdx.x;
    int d = tid & 63, q = tid >> 6;
    const float* hb = h_res + b*256*64;

    float sum = 0.f, mx = -INFINITY;
    #pragma unroll 8
    for (int k = 0; k < 64; ++k) {
        float v = hb[(q*64+k)*64 + d];
        sum += v; mx = fmaxf(mx, v);
    }
    __shared__ float sum_sh[256], max_sh[256];
    __shared__ float pm_sh[64], px_sh[64];
    sum_sh[tid] = sum; max_sh[tid] = mx;
    __syncthreads();
    if (tid < 64) {
        float tsum = sum_sh[tid] + sum_sh[64+tid] + sum_sh[128+tid] + sum_sh[192+tid];
        float tmax = fmaxf(fmaxf(max_sh[tid], max_sh[64+tid]),
                           fmaxf(max_sh[128+tid], max_sh[192+tid]));
        pm_sh[tid] = tsum * (1.f/256.f);
        px_sh[tid] = tmax;
    }
    __syncthreads();
    if (tid < 64) {
        float acc = c_b1[tid];
        #pragma unroll
        for (int e = 0; e < 64; ++e) {
            acc += pm_sh[e] * c_w1[e*64 + tid];
            acc += px_sh[e] * c_w1[(64+e)*64 + tid];
        }
        float z = (acc - bn_mean[tid]) * rsqrtf(bn_var[tid] + 1e-5f) * bn_g[tid] + bn_b[tid];
        z = elu_f(z);
        float c0 = z * c_w2[tid*2 + 0];
        float c1 = z * c_w2[tid*2 + 1];
        for (int off = 32; off > 0; off >>= 1) {
            c0 += __shfl_down(c0, off);
            c1 += __shfl_down(c1, off);
        }
        if (tid == 0) {
            out[b*2 + 0] = c0 + c_b2[0];
            out[b*2 + 1] = c1 + c_b2[1];
        }
    }
}

extern "C" void kernel_launch(void* const* d_in, const int* in_sizes, int n_in,
                              void* d_out, int out_size, void* d_ws, size_t ws_size,
                              hipStream_t stream) {
    const float* x       = (const float*)d_in[0];
    const float* proj_w  = (const float*)d_in[1];
    const float* proj_b  = (const float*)d_in[2];
    const float* s_w1    = (const float*)d_in[3];
    const float* s_b1    = (const float*)d_in[4];
    const float* ln_g    = (const float*)d_in[5];
    const float* ln_b    = (const float*)d_in[6];
    const float* s_w2    = (const float*)d_in[7];
    const float* s_b2    = (const float*)d_in[8];
    const float* gnn_w   = (const float*)d_in[9];
    const float* c_w1    = (const float*)d_in[10];
    const float* c_b1    = (const float*)d_in[11];
    const float* bn_g    = (const float*)d_in[12];
    const float* bn_b    = (const float*)d_in[13];
    const float* bn_mean = (const float*)d_in[14];
    const float* bn_var  = (const float*)d_in[15];
    const float* c_w2    = (const float*)d_in[16];
    const float* c_b2    = (const float*)d_in[17];

    float* w = (float*)d_ws;
    float* h     = w + OFF_H;
    float* hT    = w + OFF_HT;
    float* a_i   = w + OFF_AI;
    float* a_jT  = w + OFF_AJT;
    float* sa_i  = w + OFF_SAI;
    float* qa_i  = w + OFF_QAI;
    float* sa_j  = w + OFF_SAJ;
    float* qa_j  = w + OFF_QAJ;
    float* sqh   = w + OFF_SQH;
    float* rs_m  = w + OFF_RS;
    float* nr_m  = w + OFF_NR;
    float* d2_m  = w + OFF_D2;
    float* h_res = w + OFF_HRES;
    float* out   = (float*)d_out;

    k1_embed<<<512, 256, 0, stream>>>(x, proj_w, proj_b, s_w1, s_b1,
                                      h, hT, a_i, a_jT,
                                      sa_i, qa_i, sa_j, qa_j, sqh);
    k2_gram<<<512, 256, 0, stream>>>(a_i, a_jT, h, hT,
                                     sa_i, qa_i, sa_j, qa_j, sqh,
                                     rs_m, nr_m, d2_m);
    k3_pair<<<1024, 256, 0, stream>>>(a_i, a_jT, h, rs_m, nr_m, d2_m,
                                      ln_g, ln_b, s_w2, s_b2, gnn_w, h_res);
    k4_pool_cls<<<16, 256, 0, stream>>>(h_res, c_w1, c_b1, bn_g, bn_b,
                                        bn_mean, bn_var, c_w2, c_b2, out);
}